// Round 9
// baseline (249.622 us; speedup 1.0000x reference)
//
#include <hip/hip_runtime.h>

// CTC loss forward, f64 prob-domain, TWO waves per batch element (staggered
// producer/consumer). Wave0 owns states 0..255 (4/lane), wave1 owns 256..512
// (4/lane + state 512 in a 5th reg). Cross-wave dependency (state 255 -> 256)
// goes through an LDS mailbox; wave1 runs TWO barrier-periods behind wave0 so
// every mailbox value is written + lgkm-drained + barrier-separated one full
// period before it is read, and read one full period before consumption:
// no exposed LDS latency, no formal races. Raw s_barrier (no compiler drain).
// Per-wave rescale anchors; mailbox carries wave0's tote so wave1 applies an
// exact 2^k frame correction (empty-wave seeding bounds k). In-wave neighbor
// via DPP wave_shr:1. y_pred staged via global_load_lds, 3x16KB, pair-row
// gathers prefetched 2 pairs ahead.

#define Bc 64
#define Tc 1024
#define Cc 128
#define Lc 256
#define Sc 513
#define BLANKc 127
#define CHUNK 32
#define NCHUNK (Tc / CHUNK)

constexpr float EPSF = 1e-7f;

#define DPPMAXI(x, ctrl) max(x, __builtin_amdgcn_update_dpp( \
    0, x, ctrl, 0xf, 0xf, true))

__device__ __forceinline__ double dpp_wave_shr1_f64(double x) {
    // lane l <- lane l-1; lane 0 <- 0 (bound_ctrl)
    union { double d; int i[2]; } u, r;
    u.d = x;
    r.i[0] = __builtin_amdgcn_update_dpp(0, u.i[0], 0x138, 0xf, 0xf, true);
    r.i[1] = __builtin_amdgcn_update_dpp(0, u.i[1], 0x138, 0xf, 0xf, true);
    return r.d;
}

__global__ __launch_bounds__(128) void ctc_kernel(
    const int* __restrict__ y_true,        // [B, L]
    const float* __restrict__ y_pred,      // [B, T, C]
    const int* __restrict__ input_length,  // [B, 1]
    const int* __restrict__ label_length,  // [B, 1]
    float* __restrict__ out)               // [B, 1]
{
    const int b    = blockIdx.x;
    const int tid  = threadIdx.x;
    const int lane = tid & 63;
    const int wid  = tid >> 6;             // 0: states 0..255, 1: 256..512

    __shared__ float  bufs[3][CHUNK * Cc]; // 3 x 16 KB staged y_pred rows
    __shared__ double afin[Sc];
    __shared__ double mbD[2][64];          // mailbox: [63]=a3(state255), [0..62]=tote0
    __shared__ int    toteS[2];

    const int lab_len = label_length[b];
    const int in_len  = min(input_length[b], Tc);
    const float* yp = y_pred + (size_t)b * Tc * Cc;
    const int* lab = y_true + b * Lc;

    // ---- per-lane static metadata (2 label classes / lane) ----
    const int li0 = 128 * wid + 2 * lane;
    const int c0 = lab[li0], c1 = lab[li0 + 1];
    const int prev0 = (li0 > 0) ? lab[li0 - 1] : BLANKc;
    const double sm1 = (li0 > 0 && c0 != BLANKc && c0 != prev0) ? 1.0 : 0.0;
    const double sm3 = (c1 != BLANKc && c1 != c0) ? 1.0 : 0.0;

    const int S2 = 2 * lab_len + 1;
    const int s0g = 256 * wid + 4 * lane;
    int ivm[4];
    #pragma unroll
    for (int j = 0; j < 4; ++j) ivm[j] = (s0g + j < S2) ? -1 : 0;
    const int ivm4 = (wid == 1 && lane == 63 && 512 < S2) ? -1 : 0;

    auto stage = [&](int k2, float* dstbuf) {   // wave0 only
        const float* g = yp + (size_t)k2 * (CHUNK * Cc) + lane * 4;
        #pragma unroll
        for (int i = 0; i < 16; ++i) {
            __builtin_amdgcn_global_load_lds(
                (const __attribute__((address_space(1))) void*)(g + i * 256),
                (__attribute__((address_space(3))) void*)(dstbuf + i * 256),
                16, 0, 0);
        }
    };

    // ---- state ----
    double a0 = 0, a1 = 0, a2 = 0, a3 = 0, a4 = 0;   // a4 = state 512 (w1)
    double n3 = 0;          // pipelined dpp(a3)
    double crv = 0;         // corrected mailbox value (w1 lane0), else 0
    double pb, q1, q3;      // p's for the coming step
    int tote = 0; double toted = 0.0;
    double mbv_raw = 0.0, mtd_raw = 0.0;
    float sA[6], sB[6];     // pair slots {b,b',c0,c0',c1,c1'}

    auto gpair = [&](const float* rowp, float* sl) {
        sl[0] = rowp[BLANKc]; sl[1] = rowp[BLANKc + Cc];
        sl[2] = rowp[c0];     sl[3] = rowp[c0 + Cc];
        sl[4] = rowp[c1];     sl[5] = rowp[c1 + Cc];
    };
    auto expandE = [&](const float* sl) {
        pb = (double)(sl[0] + EPSF); q1 = (double)(sl[2] + EPSF);
        q3 = (double)(sl[4] + EPSF);
    };
    auto expandO = [&](const float* sl) {
        pb = (double)(sl[1] + EPSF); q1 = (double)(sl[3] + EPSF);
        q3 = (double)(sl[5] + EPSF);
    };
    auto stepfn = [&]() {
        const double nc = n3 + crv;                  // crv==0 except w1 lane0
        const double t0 = a0 + nc;
        const double t1 = __fma_rn(sm1, nc, a1 + a0);
        const double t2 = a2 + a1;
        const double t3 = __fma_rn(sm3, a1, a3 + a2);
        const double t4 = a4 + a3;                   // state 512 (w1 lane63)
        a3 = t3 * q3;
        n3 = dpp_wave_shr1_f64(a3);
        a0 = t0 * pb; a1 = t1 * q1; a2 = t2 * pb; a4 = t4 * pb;
    };
    auto mbwrite = [&](int t) {                      // wave0, top of step t:
        volatile double* md = &mbD[t & 1][0];        // post-(t-1) pair
        md[lane] = (lane == 63) ? a3 : toted;
    };
    auto mbread = [&](int idx) {                     // wave1: post-t pair
        volatile double* md = &mbD[idx & 1][0];
        mbv_raw = md[63];
        mtd_raw = md[0];
    };
    auto crvbuild = [&]() {                          // wave1, end of iteration
        int ki = __double2int_rn(mtd_raw) - tote;    // mt - tote1
        ki = min(max(ki, -960), 960);
        const double corr = __hiloint2double((1023 + ki) << 20, 0);
        const double cv = mbv_raw * corr;
        crv = (lane == 0) ? cv : 0.0;
    };
    auto rescale = [&]() {
        int e =        ivm[0] & (__double2hiint(a0) >> 20);
        e = max(e, ivm[1] & (__double2hiint(a1) >> 20));
        e = max(e, ivm[2] & (__double2hiint(a2) >> 20));
        e = max(e, ivm[3] & (__double2hiint(a3) >> 20));
        e = max(e, ivm4   & (__double2hiint(a4) >> 20));
        e = DPPMAXI(e, 0x111); e = DPPMAXI(e, 0x112); e = DPPMAXI(e, 0x114);
        e = DPPMAXI(e, 0x118); e = DPPMAXI(e, 0x142); e = DPPMAXI(e, 0x143);
        const int emax = __builtin_amdgcn_readlane(e, 63);
        if (emax == 0) {                 // wave empty: seed w1's frame to w0's
            if (wid) tote = __double2int_rn(mtd_raw);
            return;
        }
        const int sexp = min(max(2046 - emax, 1), 2045);
        const double sc = __hiloint2double(sexp << 20, 0);   // 2^(sexp-1023)
        const int d = 1023 - sexp;
        tote += d; toted += (double)d;
        a0 *= sc; a1 *= sc; a2 *= sc; a3 *= sc; a4 *= sc;
        n3 *= sc; crv *= sc;
    };

    // ---- prologue ----
    if (wid == 0) {
        stage(0, bufs[0]); stage(1, bufs[1]); stage(2, bufs[2]);
        __builtin_amdgcn_s_waitcnt(0x0F70);          // vmcnt(0)
    }
    __builtin_amdgcn_s_barrier();                    // period-0 boundary

    if (wid == 0 && lane == 0) {
        a0 = (double)(bufs[0][BLANKc] + EPSF);               // s=0
        if (lab_len > 0) a1 = (double)(bufs[0][c0] + EPSF);  // s=1
    }
    {   // prime: row 1 p's + pairs (2,3)->sA, (4,5)->sB   (both waves)
        const float* r1 = bufs[0] + Cc;
        pb = (double)(r1[BLANKc] + EPSF);
        q1 = (double)(r1[c0] + EPSF);
        q3 = (double)(r1[c1] + EPSF);
        gpair(bufs[0] + 2 * Cc, sA);
        gpair(bufs[0] + 4 * Cc, sB);
    }

    if (wid == 0) {
        // ================= WAVE 0 : period p = step t =================
        // step 1
        mbwrite(1);
        if (1 < in_len) stepfn();
        __builtin_amdgcn_s_waitcnt(0xC07F);          // lgkmcnt(0)
        __builtin_amdgcn_s_barrier();
        // chunk 0 pairs: steps (2,3)..(30,31)
        #pragma unroll 2
        for (int pr = 0; pr < 15; ++pr) {
            const int t = 2 + 2 * pr;
            float* cur = (pr & 1) ? sB : sA;
            mbwrite(t);
            expandE(cur);
            if (t < in_len) stepfn();
            __builtin_amdgcn_s_waitcnt(0xC07F);
            __builtin_amdgcn_s_barrier();
            mbwrite(t + 1);
            expandO(cur);
            {   const float* nxt = (t + 4 < 32) ? (bufs[0] + (t + 4) * Cc)
                                                : (bufs[1] + (t + 4 - 32) * Cc);
                gpair(nxt, cur); }
            if (t + 1 < in_len) stepfn();
            if (pr == 14) rescale();
            __builtin_amdgcn_s_waitcnt(0xC07F);
            __builtin_amdgcn_s_barrier();
        }
        // chunks 1..31 (slot parity inverted: 15 pairs consumed in chunk 0)
        #pragma unroll 1
        for (int c = 1; c < NCHUNK; ++c) {
            const int base = 32 * c;
            const float* rb  = bufs[c % 3];
            const float* rbn = bufs[(c + 1) % 3];
            #pragma unroll 2
            for (int pr = 0; pr < 16; ++pr) {
                const int t = base + 2 * pr;
                float* cur = (pr & 1) ? sA : sB;
                mbwrite(t);
                if (pr == 0) {
                    __builtin_amdgcn_s_waitcnt(0x0F70);   // stage(c+1) landed
                    if (c + 2 < NCHUNK) stage(c + 2, bufs[(c + 2) % 3]);
                }
                expandE(cur);
                if (t < in_len) stepfn();
                __builtin_amdgcn_s_waitcnt(0xC07F);
                __builtin_amdgcn_s_barrier();
                mbwrite(t + 1);
                expandO(cur);
                {   const float* nxt = (2 * pr + 4 < 32)
                        ? (rb + (2 * pr + 4) * Cc)
                        : (rbn + (2 * pr + 4 - 32) * Cc);
                    gpair(nxt, cur); }
                if (t + 1 < in_len) stepfn();
                if (pr == 15) rescale();
                __builtin_amdgcn_s_waitcnt(0xC07F);
                __builtin_amdgcn_s_barrier();
            }
        }
        __builtin_amdgcn_s_barrier();                // period 1024
        __builtin_amdgcn_s_barrier();                // period 1025
    } else {
        // ============ WAVE 1 : period p = step t + 2 (lag 2) ============
        __builtin_amdgcn_s_barrier();                // period 1
        __builtin_amdgcn_s_barrier();                // period 2
        // step 1 (period 3)
        mbread(2);                                   // post-1 pair (for step 2)
        if (1 < in_len) stepfn();
        crvbuild();
        __builtin_amdgcn_s_barrier();
        // chunk 0 pairs
        #pragma unroll 2
        for (int pr = 0; pr < 15; ++pr) {
            const int t = 2 + 2 * pr;
            float* cur = (pr & 1) ? sB : sA;
            mbread(t + 1);                           // post-t pair
            expandE(cur);
            if (t < in_len) stepfn();
            crvbuild();
            __builtin_amdgcn_s_barrier();
            mbread(t + 2);                           // post-(t+1) pair
            expandO(cur);
            {   const float* nxt = (t + 4 < 32) ? (bufs[0] + (t + 4) * Cc)
                                                : (bufs[1] + (t + 4 - 32) * Cc);
                gpair(nxt, cur); }
            if (t + 1 < in_len) stepfn();
            crvbuild();
            if (pr == 14) rescale();
            __builtin_amdgcn_s_barrier();
        }
        // chunks 1..31
        #pragma unroll 1
        for (int c = 1; c < NCHUNK; ++c) {
            const int base = 32 * c;
            const float* rb  = bufs[c % 3];
            const float* rbn = bufs[(c + 1) % 3];
            #pragma unroll 2
            for (int pr = 0; pr < 16; ++pr) {
                const int t = base + 2 * pr;
                float* cur = (pr & 1) ? sA : sB;
                mbread(t + 1);
                expandE(cur);
                if (t < in_len) stepfn();
                crvbuild();
                __builtin_amdgcn_s_barrier();
                mbread(t + 2);
                expandO(cur);
                {   const float* nxt = (2 * pr + 4 < 32)
                        ? (rb + (2 * pr + 4) * Cc)
                        : (rbn + (2 * pr + 4 - 32) * Cc);
                    gpair(nxt, cur); }
                if (t + 1 < in_len) stepfn();
                crvbuild();
                if (pr == 15) rescale();
                __builtin_amdgcn_s_barrier();
            }
        }
    }

    // ---- epilogue ----
    afin[s0g + 0] = a0; afin[s0g + 1] = a1;
    afin[s0g + 2] = a2; afin[s0g + 3] = a3;
    if (wid == 1 && lane == 63) afin[512] = a4;
    if (lane == 0) toteS[wid] = tote;
    __syncthreads();
    if (tid == 0) {
        const int ib = 2 * lab_len;
        const int il = (ib - 1 > 0) ? (ib - 1) : 0;
        const double vb = afin[ib];
        const double vl = (lab_len > 0) ? afin[il] : 0.0;
        const int tb = toteS[(ib >= 256) ? 1 : 0];
        const int tl = toteS[(il >= 256) ? 1 : 0];
        int kd = tl - tb;
        kd = min(max(kd, -1000), 1000);
        const double corr = __hiloint2double((1023 + kd) << 20, 0);
        const double loss = -(log(vb + vl * corr)
                              + (double)tb * 0.6931471805599453);
        out[b] = (float)loss;
    }
}

extern "C" void kernel_launch(void* const* d_in, const int* in_sizes, int n_in,
                              void* d_out, int out_size, void* d_ws, size_t ws_size,
                              hipStream_t stream) {
    const int*   y_true       = (const int*)d_in[0];
    const float* y_pred       = (const float*)d_in[1];
    const int*   input_length = (const int*)d_in[2];
    const int*   label_length = (const int*)d_in[3];
    float* out = (float*)d_out;

    ctc_kernel<<<Bc, 128, 0, stream>>>(y_true, y_pred, input_length,
                                       label_length, out);
}

// Round 10
// 149.909 us; speedup vs baseline: 1.6652x; 1.6652x over previous
//
#include <hip/hip_runtime.h>

// CTC loss forward, f64 prob-domain with power-of-2 rescaling.
// One WAVE per batch element; lane l holds states 8l..8l+7 (+state 512 on
// lane 63) in f64 regs. No barriers/bpermute in T-loop; neighbor via DPP
// wave_shr:1, pipelined across steps. Two-phase stepfn (all sums, then all
// muls) exposes 9 independent chains. p-values are expanded ONE FULL STEP
// AHEAD into alternating f64 sets (peE/peO), so LDS-gather + cvt latency is
// off the critical path. y_pred staged via global_load_lds into 3x16KB LDS
// buffers; pair-row gathers prefetched 2 pairs ahead, seamless across chunk
// boundaries. Rescale once per 32-step chunk: int-exponent masked max
// (invalid states excluded from anchor, not zeroed -- strictly-forward
// flow), exact 2^-e scaling. f64 window ~1022 bits vs ~800 worst-case need.
//
// NOTE (R9): a 2-wave producer/consumer split with per-step s_barrier
// mailbox hand-off was tried and REGRESSED 2x (90 -> 185 us profiled):
// the per-step cross-wave barrier rendezvous (~200 cy) costs more than the
// entire f64 update it parallelizes. The serial T-chain must stay in-wave.

#define Bc 64
#define Tc 1024
#define Cc 128
#define Lc 256
#define Sc 513
#define BLANKc 127
#define CHUNK 32
#define NCHUNK (Tc / CHUNK)

constexpr float EPSF = 1e-7f;

#define DPPMAXI(x, ctrl) max(x, __builtin_amdgcn_update_dpp( \
    0, x, ctrl, 0xf, 0xf, true))

__device__ __forceinline__ double dpp_wave_shr1_f64(double x) {
    // lane l <- lane l-1; lane 0 <- 0 (bound_ctrl)
    union { double d; int i[2]; } u, r;
    u.d = x;
    r.i[0] = __builtin_amdgcn_update_dpp(0, u.i[0], 0x138, 0xf, 0xf, true);
    r.i[1] = __builtin_amdgcn_update_dpp(0, u.i[1], 0x138, 0xf, 0xf, true);
    return r.d;
}

__global__ __launch_bounds__(64) void ctc_kernel(
    const int* __restrict__ y_true,        // [B, L]
    const float* __restrict__ y_pred,      // [B, T, C]
    const int* __restrict__ input_length,  // [B, 1]
    const int* __restrict__ label_length,  // [B, 1]
    float* __restrict__ out)               // [B, 1]
{
    const int b = blockIdx.x;
    const int lane = threadIdx.x;          // 0..63, one wave per block

    __shared__ float bufs[3][CHUNK * Cc];  // 3 x 16 KB staged y_pred rows
    __shared__ double afin[Sc];

    const int lab_len = label_length[b];
    const int in_len  = min(input_length[b], Tc);
    const float* yp = y_pred + (size_t)b * Tc * Cc;
    const int* lab = y_true + b * Lc;

    // ---- per-lane static metadata ----
    const int i0 = 4 * lane;
    const int c0 = lab[i0], c1 = lab[i0 + 1], c2 = lab[i0 + 2], c3 = lab[i0 + 3];
    const double sm0 = (lane == 0) ? 0.0
                       : ((c0 != BLANKc && c0 != lab[i0 - 1]) ? 1.0 : 0.0);
    const double sm1 = (c1 != BLANKc && c1 != c0) ? 1.0 : 0.0;
    const double sm2 = (c2 != BLANKc && c2 != c1) ? 1.0 : 0.0;
    const double sm3 = (c3 != BLANKc && c3 != c2) ? 1.0 : 0.0;

    const int S2 = 2 * lab_len + 1;        // validity: state < S2
    int ivm[8];
    #pragma unroll
    for (int j = 0; j < 8; ++j) ivm[j] = (8 * lane + j < S2) ? -1 : 0;
    const int ivm8 = (lane == 63 && 512 < S2) ? -1 : 0;

    auto stage = [&](int k2, float* dstbuf) {
        const float* g = yp + (size_t)k2 * (CHUNK * Cc) + lane * 4;
        #pragma unroll
        for (int i = 0; i < 16; ++i) {
            __builtin_amdgcn_global_load_lds(
                (const __attribute__((address_space(1))) void*)(g + i * 256),
                (__attribute__((address_space(3))) void*)(dstbuf + i * 256),
                16, 0, 0);
        }
    };

    // ---- alpha registers (f64) ----
    double a0 = 0, a1 = 0, a2 = 0, a3 = 0, a4 = 0, a5 = 0, a6 = 0, a7 = 0, a8 = 0;
    double n7 = 0;                         // pipelined dpp(a7)
    int tote = 0;

    // two f64 p-sets, expanded one step ahead of use
    double Eb, E1, E3, E5, E7;             // even-row p's
    double Ob, O1, O3, O5, O7;             // odd-row p's

    // pair slots: even idx = row 2q, odd idx = row 2q+1; slot[q&1] holds pair q
    float s01[10], s23[10];

    auto gpair = [&](const float* rowp, float* sl) {
        sl[0] = rowp[BLANKc]; sl[1] = rowp[BLANKc + Cc];
        sl[2] = rowp[c0];     sl[3] = rowp[c0 + Cc];
        sl[4] = rowp[c1];     sl[5] = rowp[c1 + Cc];
        sl[6] = rowp[c2];     sl[7] = rowp[c2 + Cc];
        sl[8] = rowp[c3];     sl[9] = rowp[c3 + Cc];
    };
    auto expandE = [&](const float* sl) {   // even element of a pair slot
        Eb = (double)(sl[0] + EPSF); E1 = (double)(sl[2] + EPSF);
        E3 = (double)(sl[4] + EPSF); E5 = (double)(sl[6] + EPSF);
        E7 = (double)(sl[8] + EPSF);
    };
    auto expandO = [&](const float* sl) {   // odd element of a pair slot
        Ob = (double)(sl[1] + EPSF); O1 = (double)(sl[3] + EPSF);
        O3 = (double)(sl[5] + EPSF); O5 = (double)(sl[7] + EPSF);
        O7 = (double)(sl[9] + EPSF);
    };
    auto stepE = [&]() {
        const double t8 = a8 + a7;
        const double t7 = __fma_rn(sm3, a5, a7 + a6);
        const double t6 = a6 + a5;
        const double t5 = __fma_rn(sm2, a3, a5 + a4);
        const double t4 = a4 + a3;
        const double t3 = __fma_rn(sm1, a1, a3 + a2);
        const double t2 = a2 + a1;
        const double t1 = __fma_rn(sm0, n7, a1 + a0);
        const double t0 = a0 + n7;
        a7 = t7 * E7;
        n7 = dpp_wave_shr1_f64(a7);
        a8 = t8 * Eb; a6 = t6 * Eb; a5 = t5 * E5; a4 = t4 * Eb;
        a3 = t3 * E3; a2 = t2 * Eb; a1 = t1 * E1; a0 = t0 * Eb;
    };
    auto stepO = [&]() {
        const double t8 = a8 + a7;
        const double t7 = __fma_rn(sm3, a5, a7 + a6);
        const double t6 = a6 + a5;
        const double t5 = __fma_rn(sm2, a3, a5 + a4);
        const double t4 = a4 + a3;
        const double t3 = __fma_rn(sm1, a1, a3 + a2);
        const double t2 = a2 + a1;
        const double t1 = __fma_rn(sm0, n7, a1 + a0);
        const double t0 = a0 + n7;
        a7 = t7 * O7;
        n7 = dpp_wave_shr1_f64(a7);
        a8 = t8 * Ob; a6 = t6 * Ob; a5 = t5 * O5; a4 = t4 * Ob;
        a3 = t3 * O3; a2 = t2 * Ob; a1 = t1 * O1; a0 = t0 * Ob;
    };
    auto rescale = [&]() {
        int e;
        e =        ivm[0] & (__double2hiint(a0) >> 20);
        e = max(e, ivm[1] & (__double2hiint(a1) >> 20));
        e = max(e, ivm[2] & (__double2hiint(a2) >> 20));
        e = max(e, ivm[3] & (__double2hiint(a3) >> 20));
        e = max(e, ivm[4] & (__double2hiint(a4) >> 20));
        e = max(e, ivm[5] & (__double2hiint(a5) >> 20));
        e = max(e, ivm[6] & (__double2hiint(a6) >> 20));
        e = max(e, ivm[7] & (__double2hiint(a7) >> 20));
        e = max(e, ivm8   & (__double2hiint(a8) >> 20));
        e = DPPMAXI(e, 0x111);   // row_shr:1
        e = DPPMAXI(e, 0x112);   // row_shr:2
        e = DPPMAXI(e, 0x114);   // row_shr:4
        e = DPPMAXI(e, 0x118);   // row_shr:8
        e = DPPMAXI(e, 0x142);   // row_bcast:15
        e = DPPMAXI(e, 0x143);   // row_bcast:31
        const int emax = __builtin_amdgcn_readlane(e, 63);
        int sexp = 2046 - emax;                      // biased exp of 2^(1023-emax)
        sexp = min(max(sexp, 1), 2045);
        const double sc = __hiloint2double(sexp << 20, 0);   // exact power of 2
        tote += 1023 - sexp;
        a0 *= sc; a1 *= sc; a2 *= sc; a3 *= sc; a4 *= sc;
        a5 *= sc; a6 *= sc; a7 *= sc; a8 *= sc;
        n7 *= sc;
    };

    // ---- prologue ----
    stage(0, bufs[0]);
    stage(1, bufs[1]);
    stage(2, bufs[2]);
    __builtin_amdgcn_s_waitcnt(0x0F70);  // vmcnt(0): DMA landed; 1 wave, no barrier

    if (lane == 0) {
        a0 = (double)(bufs[0][BLANKc] + EPSF);               // s=0
        if (lab_len > 0) a1 = (double)(bufs[0][c0] + EPSF);  // s=1
    }

    // prime slots & pe pipeline:
    // pair q=1 (rows 2,3) -> slot1; pair q=2 (rows 4,5) -> slot0
    gpair(bufs[0] + 2 * Cc, s23);
    gpair(bufs[0] + 4 * Cc, s01);
    {   // row 1 direct -> odd set; row 2 -> even set
        const float* r1 = bufs[0] + 1 * Cc;
        Ob = (double)(r1[BLANKc] + EPSF); O1 = (double)(r1[c0] + EPSF);
        O3 = (double)(r1[c1] + EPSF);     O5 = (double)(r1[c2] + EPSF);
        O7 = (double)(r1[c3] + EPSF);
    }
    expandE(s23);                        // row 2

    // ---- step t=1 (lone odd step) ----
    if (1 < in_len) stepO();
    expandO(s23);                        // row 3 for t=3

    // ---- chunk 0: pairs q=1..15 (rows 2..31) ----
    {
        const float* rb  = bufs[0];
        const float* rbn = bufs[1];
        #pragma unroll
        for (int qi = 1; qi < 16; ++qi) {
            const int rr = 2 * qi;
            if (rr < in_len) stepE();
            expandE((qi & 1) ? s01 : s23);     // row rr+2 from slot[(qi+1)&1]
            if (rr + 1 < in_len) stepO();
            expandO((qi & 1) ? s01 : s23);     // row rr+3
            const float* nxt = (rr + 4 < CHUNK) ? (rb + (rr + 4) * Cc)
                                                : (rbn + (rr + 4 - CHUNK) * Cc);
            gpair(nxt, (qi & 1) ? s23 : s01);  // pair qi+2 -> slot[qi&1]
        }
    }
    rescale();
    __builtin_amdgcn_s_waitcnt(0x0F70);
    stage(3, bufs[0]);

    // ---- chunks 1..31: unified pair pipeline ----
    for (int k = 1; k < NCHUNK; ++k) {
        const float* rb  = bufs[k % 3];
        const float* rbn = bufs[(k + 1) % 3];   // k=31: dead reads, safe
        const int tbase = k * CHUNK;
        if (tbase + CHUNK <= in_len) {
            #pragma unroll
            for (int qi = 0; qi < 16; ++qi) {
                const int rr = 2 * qi;
                stepE();
                expandE((qi & 1) ? s01 : s23);
                stepO();
                expandO((qi & 1) ? s01 : s23);
                const float* nxt = (rr + 4 < CHUNK) ? (rb + (rr + 4) * Cc)
                                                    : (rbn + (rr + 4 - CHUNK) * Cc);
                gpair(nxt, (qi & 1) ? s23 : s01);
            }
        } else {
            #pragma unroll 2
            for (int qi = 0; qi < 16; ++qi) {
                const int rr = 2 * qi;
                if (tbase + rr < in_len) stepE();
                expandE((qi & 1) ? s01 : s23);
                if (tbase + rr + 1 < in_len) stepO();
                expandO((qi & 1) ? s01 : s23);
                const float* nxt = (rr + 4 < CHUNK) ? (rb + (rr + 4) * Cc)
                                                    : (rbn + (rr + 4 - CHUNK) * Cc);
                gpair(nxt, (qi & 1) ? s23 : s01);
            }
        }
        rescale();
        __builtin_amdgcn_s_waitcnt(0x0F70);     // stage(k+2) landed
        if (k + 3 < NCHUNK) stage(k + 3, bufs[(k + 3) % 3]);
    }

    // ---- epilogue ----
    afin[8 * lane + 0] = a0; afin[8 * lane + 1] = a1;
    afin[8 * lane + 2] = a2; afin[8 * lane + 3] = a3;
    afin[8 * lane + 4] = a4; afin[8 * lane + 5] = a5;
    afin[8 * lane + 6] = a6; afin[8 * lane + 7] = a7;
    if (lane == 63) afin[512] = a8;
    __syncthreads();
    if (lane == 0) {
        const double eb = afin[2 * lab_len];
        const double el = (lab_len > 0) ? afin[2 * lab_len - 1] : 0.0;
        const double loss = -(log(eb + el) + (double)tote * 0.6931471805599453);
        out[b] = (float)loss;
    }
}

extern "C" void kernel_launch(void* const* d_in, const int* in_sizes, int n_in,
                              void* d_out, int out_size, void* d_ws, size_t ws_size,
                              hipStream_t stream) {
    const int*   y_true       = (const int*)d_in[0];
    const float* y_pred       = (const float*)d_in[1];
    const int*   input_length = (const int*)d_in[2];
    const int*   label_length = (const int*)d_in[3];
    float* out = (float*)d_out;

    ctc_kernel<<<Bc, 64, 0, stream>>>(y_true, y_pred, input_length,
                                      label_length, out);
}